// Round 11
// baseline (247.835 us; speedup 1.0000x reference)
//
#include <hip/hip_runtime.h>

// Zero timestep t (t & 3 == mask_idx) of x: [8, 8192, 512] fp32.
//
// R7 post-mortem: three different fused masked-copy kernels all land at
// 71-80us (~3.3 TB/s logical) vs the 37us fused floor, while in the SAME
// environment the harness fill sustains 6.6 TB/s and m13's canonical f32x4
// copy hits 6.29 TB/s. Never measured here: a branch-free pure copy.
//
// This round: A/B-decisive split into the two known-fast patterns:
//   1) copy_all    — canonical grid-stride f32x4 copy (out = x, all 128 MiB)
//   2) fill_masked — zero the masked quarter (pure stores, fill pattern)
// Extra traffic vs fused ideal: +33.5MB rewrite +33.5MB masked read
// -> ~301 MB -> ~48us at copy rate. If copy is fast: bench ~205-212 (win,
// and the fused branch structure was the problem). If bench stays ~228:
// the environment caps mixed streams and R7 was already near ceiling.

#define PERIOD 4

typedef float f32x4 __attribute__((ext_vector_type(4)));

__global__ __launch_bounds__(256)
void copy_all(const f32x4* __restrict__ x, f32x4* __restrict__ out, int n4) {
    const int stride = gridDim.x * blockDim.x;
    int i = blockIdx.x * blockDim.x + threadIdx.x;
    #pragma unroll 4
    for (; i < n4; i += stride)
        out[i] = x[i];
}

__global__ __launch_bounds__(256)
void fill_masked(const int* __restrict__ mask_p, f32x4* __restrict__ out, int nq) {
    // nq = f32x4 count of the masked quarter = n4/4.
    // Timestep = 128 f32x4; frame (PERIOD timesteps) = 512 f32x4.
    const int m = *mask_p;                       // uniform scalar load
    const f32x4 zero = (f32x4){0.f, 0.f, 0.f, 0.f};
    const int stride = gridDim.x * blockDim.x;
    for (int j = blockIdx.x * blockDim.x + threadIdx.x; j < nq; j += stride) {
        const int frame = j >> 7;
        const int off   = j & 127;
        out[frame * 512 + m * 128 + off] = zero; // contiguous 2KiB runs
    }
}

// Generic fused fallback (any size).
__global__ __launch_bounds__(256)
void pd_mask_generic(const f32x4* __restrict__ x,
                     const int* __restrict__ mask_p,
                     f32x4* __restrict__ out, int n4) {
    const int m = *mask_p;
    const f32x4 zero = (f32x4){0.f, 0.f, 0.f, 0.f};
    const int stride = gridDim.x * blockDim.x;
    for (int i = blockIdx.x * blockDim.x + threadIdx.x; i < n4; i += stride) {
        const int t = i >> 7;
        out[i] = ((t & (PERIOD - 1)) == m) ? zero : x[i];
    }
}

extern "C" void kernel_launch(void* const* d_in, const int* in_sizes, int n_in,
                              void* d_out, int out_size, void* d_ws, size_t ws_size,
                              hipStream_t stream) {
    const f32x4* x      = (const f32x4*)d_in[0];
    const int*   mask_p = (const int*)d_in[1];
    f32x4*       out    = (f32x4*)d_out;

    const int n4 = out_size / 4;                 // 8388608 f32x4
    if ((n4 & 511) == 0) {
        // 1) branch-free canonical copy of everything
        copy_all<<<2048, 256, 0, stream>>>(x, out, n4);
        // 2) overwrite the masked quarter with zeros (pure stores)
        const int nq = n4 / 4;                   // 2097152 f32x4
        fill_masked<<<1024, 256, 0, stream>>>(mask_p, out, nq);
    } else {
        int grid = (n4 + 255) / 256;
        if (grid > 2048) grid = 2048;
        pd_mask_generic<<<grid, 256, 0, stream>>>(x, mask_p, out, n4);
    }
}

// Round 13
// 218.273 us; speedup vs baseline: 1.1354x; 1.1354x over previous
//
#include <hip/hip_runtime.h>

// Zero timestep t (t & 3 == mask_idx) of x: [8, 8192, 512] fp32.
//
// R11 verdict: branch-free canonical copy = 83us, 2.4 TB/s HBM, NOT
// HBM-bound (201 MB traffic would take 31us at the fill's 6.4 TB/s).
// Read-return path is the limit: ~4 outstanding 16B loads/lane (VGPR=16)
// x ~1200cy loaded latency ~= 2.4 TB/s. This round attacks read MLP +
// read latency on the best-known skeleton (R7 block-contiguous):
//   - 16-deep clustered loads (64 data VGPRs in flight, 4x R11 depth)
//   - __builtin_nontemporal_load on x (streaming; skip L2/MALL
//     allocate-evict churn against the poison-dirtied cache)
//
// Geometry (R7): 1024 blocks x 512 threads x 16 iters, block streams
// 128 KiB contiguous; k advances t by exactly 4 so phase = (tid>>7)&3 is
// loop-invariant and wave-uniform: 2 of 8 waves per block are pure
// zero-store waves (never load), 6 are deep-clustered copy waves.

#define PERIOD 4

typedef float f32x4 __attribute__((ext_vector_type(4)));

__global__ __launch_bounds__(512)
void pd_mask_deep(const f32x4* __restrict__ x,
                  const int* __restrict__ mask_p,
                  f32x4* __restrict__ out) {
    constexpr int ITERS = 16;
    constexpr int BLOCK = 512;
    const int tid  = threadIdx.x;
    const int base = blockIdx.x * (BLOCK * ITERS) + tid;
    const int m = *mask_p;                       // uniform scalar load
    const int phase = (tid >> 7) & 3;            // t&3, loop-invariant
    if (phase == m) {
        const f32x4 zero = (f32x4){0.f, 0.f, 0.f, 0.f};
        #pragma unroll
        for (int k = 0; k < ITERS; ++k)
            out[base + k * BLOCK] = zero;
    } else {
        f32x4 v[ITERS];                          // 64 data VGPRs in flight
        #pragma unroll
        for (int k = 0; k < ITERS; ++k)
            v[k] = __builtin_nontemporal_load(&x[base + k * BLOCK]);
        #pragma unroll
        for (int k = 0; k < ITERS; ++k)
            out[base + k * BLOCK] = v[k];
    }
}

// Generic fallback (any size).
__global__ __launch_bounds__(256)
void pd_mask_generic(const f32x4* __restrict__ x,
                     const int* __restrict__ mask_p,
                     f32x4* __restrict__ out, int n4) {
    const int m = *mask_p;
    const f32x4 zero = (f32x4){0.f, 0.f, 0.f, 0.f};
    const int stride = gridDim.x * blockDim.x;
    for (int i = blockIdx.x * blockDim.x + threadIdx.x; i < n4; i += stride) {
        const int t = i >> 7;
        out[i] = ((t & (PERIOD - 1)) == m) ? zero : x[i];
    }
}

extern "C" void kernel_launch(void* const* d_in, const int* in_sizes, int n_in,
                              void* d_out, int out_size, void* d_ws, size_t ws_size,
                              hipStream_t stream) {
    const f32x4* x      = (const f32x4*)d_in[0];
    const int*   mask_p = (const int*)d_in[1];
    f32x4*       out    = (f32x4*)d_out;

    const int n4 = out_size / 4;                 // 8388608 f32x4
    constexpr int GRID = 1024, BLOCK = 512, ITERS = 16;

    if (n4 == GRID * BLOCK * ITERS) {
        pd_mask_deep<<<GRID, BLOCK, 0, stream>>>(x, mask_p, out);
    } else {
        int grid = (n4 + 255) / 256;
        if (grid > 2048) grid = 2048;
        pd_mask_generic<<<grid, 256, 0, stream>>>(x, mask_p, out, n4);
    }
}

// Round 15
// 218.185 us; speedup vs baseline: 1.1359x; 1.0004x over previous
//
#include <hip/hip_runtime.h>

// Zero timestep t (t & 3 == mask_idx) of x: [8, 8192, 512] fp32.
//
// R13: 16-deep nt-load, 16 waves/CU -> ~61us (3.85 TB/s bytes-touched),
// already faster per-byte than the harness's own d2d restore (~3.4 TB/s).
// Write-only fills do 6.7 TB/s; L2-hit reads ubench at 34.5 TB/s -> CU
// read-return path fine; hypothesis: per-CU outstanding-miss (MSHR) cap.
// This round: SAME in-flight product, DOUBLE the waves (32/CU x 8-deep):
// 2048 blocks x 512 thr x 8 iters, v[8] (32 data VGPR), bounds(512,8).
// If waves help: 50-55us. If unchanged: MSHR-capped, declare roofline.
//
// Phase: base = bid*4096 + k*512 + tid; 512 f32x4 = 4 timesteps per k, so
// t advances by 4 each iter -> phase = (tid>>7)&3 loop-invariant,
// wave-uniform (2-wave granularity). 2 of 8 waves pure zero-store.

#define PERIOD 4

typedef float f32x4 __attribute__((ext_vector_type(4)));

__global__ __launch_bounds__(512, 8)
void pd_mask_occ(const f32x4* __restrict__ x,
                 const int* __restrict__ mask_p,
                 f32x4* __restrict__ out) {
    constexpr int ITERS = 8;
    constexpr int BLOCK = 512;
    const int tid  = threadIdx.x;
    const int base = blockIdx.x * (BLOCK * ITERS) + tid;
    const int m = *mask_p;                       // uniform scalar load
    const int phase = (tid >> 7) & 3;            // t&3, loop-invariant
    if (phase == m) {
        const f32x4 zero = (f32x4){0.f, 0.f, 0.f, 0.f};
        #pragma unroll
        for (int k = 0; k < ITERS; ++k)
            out[base + k * BLOCK] = zero;
    } else {
        f32x4 v[ITERS];                          // 32 data VGPRs in flight
        #pragma unroll
        for (int k = 0; k < ITERS; ++k)
            v[k] = __builtin_nontemporal_load(&x[base + k * BLOCK]);
        #pragma unroll
        for (int k = 0; k < ITERS; ++k)
            out[base + k * BLOCK] = v[k];
    }
}

// Generic fallback (any size).
__global__ __launch_bounds__(256)
void pd_mask_generic(const f32x4* __restrict__ x,
                     const int* __restrict__ mask_p,
                     f32x4* __restrict__ out, int n4) {
    const int m = *mask_p;
    const f32x4 zero = (f32x4){0.f, 0.f, 0.f, 0.f};
    const int stride = gridDim.x * blockDim.x;
    for (int i = blockIdx.x * blockDim.x + threadIdx.x; i < n4; i += stride) {
        const int t = i >> 7;
        out[i] = ((t & (PERIOD - 1)) == m) ? zero : x[i];
    }
}

extern "C" void kernel_launch(void* const* d_in, const int* in_sizes, int n_in,
                              void* d_out, int out_size, void* d_ws, size_t ws_size,
                              hipStream_t stream) {
    const f32x4* x      = (const f32x4*)d_in[0];
    const int*   mask_p = (const int*)d_in[1];
    f32x4*       out    = (f32x4*)d_out;

    const int n4 = out_size / 4;                 // 8388608 f32x4
    constexpr int GRID = 2048, BLOCK = 512, ITERS = 8;

    if (n4 == GRID * BLOCK * ITERS) {
        pd_mask_occ<<<GRID, BLOCK, 0, stream>>>(x, mask_p, out);
    } else {
        int grid = (n4 + 255) / 256;
        if (grid > 2048) grid = 2048;
        pd_mask_generic<<<grid, 256, 0, stream>>>(x, mask_p, out, n4);
    }
}